// Round 21
// baseline (91.421 us; speedup 1.0000x reference)
//
#include <hip/hip_runtime.h>
#include <hip/hip_bf16.h>

// Problem: B=4, S=4096, D=256 single-head causal attention, fp32 in/out.
// ALL tensors in MFMA-fragment order (fragment = contiguous 1KB, lane*16):
//  Qf @0:  strip s16=row>>4: 8KB; frag kk at (s16*8+kk)*1024.
//          Q PRE-SCALED by 0.0625*log2(e) -> scores in LOG2 domain (bare exp2).
//  KV @8MB: per (batch, kv-tile t<64) 64KB: K frags [0..32K) (nf*8+kk)*1024;
//           V frags [32K..64K) (ks*16+n)*1024
//  O1/O2/O3 bf16 partials @24/32/40MB; ML fp32 [4][16384][2] @48MB (m in log2).
// attn_fa: 256 blocks x 512 thr (8 waves x 16 rows, 1 block/CU, 2 waves/SIMD).
// Swapped QK^T (S^T = mfma(K,Q), q lane-local), log2 softmax, defer-max,
// lazy-l, va-hoist, counted-vmcnt KV dbuf.
// R21: INTRA-TILE HALF-SPLIT — each 64-kv tile = two sequential 32-kv online
// updates. softmax(half0) depends only on nf01, so its VALU overlaps the
// in-flight QK MFMAs of nf23; softmax(half1) overlaps PV(half0). Shortens
// the per-tile serial chain without touching barriers/staging.

#define SEQ 4096
#define DIM 256
#define NBATCH 4
#define KVBLK 64
#define KVT_BYTES 65536

#define QB_OFF   0
#define KV_OFF   (8u*1024*1024)
#define O1_OFF   (24u*1024*1024)
#define O2_OFF   (32u*1024*1024)
#define O3_OFF   (40u*1024*1024)
#define ML_OFF   (48u*1024*1024)

// 0.0625 * log2(e)
#define QSCALE 0.09016844f
// 8 nats in bits
#define DEFER_THR 11.5415603f

typedef __attribute__((ext_vector_type(8))) short bf16x8;
typedef __attribute__((ext_vector_type(4))) float f32x4;
typedef __attribute__((ext_vector_type(4))) unsigned short us4;

static __device__ inline unsigned short f2bf(float f) {
  unsigned int u = __float_as_uint(f);
  u += 0x7FFFu + ((u >> 16) & 1u);
  return (unsigned short)(u >> 16);
}
static __device__ inline float bf2f(unsigned short u) {
  return __uint_as_float(((unsigned int)u) << 16);
}

// ---------------- Kernel 1: fused QKV projection (z fused; x read once) ----------------
// grid (128, 4), block 256 (4 waves, 2 blocks/CU).
__global__ __launch_bounds__(256) void qkv_gemm(
    const float* __restrict__ x, const float* __restrict__ Wq,
    const float* __restrict__ Wk, const float* __restrict__ Wv,
    char* __restrict__ qbf, char* __restrict__ kv)
{
  __shared__ unsigned short A_lds[128][40];
  __shared__ unsigned short B_lds[3][64][40];

  const int tid = threadIdx.x;
  const int lane = tid & 63;
  const int w = tid >> 6;
  const int lo = lane & 15, hi = lane >> 4;
  const int mb = blockIdx.x * 128;
  const int nb = blockIdx.y * 64;
  const float* Ws[3] = { Wq, Wk, Wv };

  f32x4 acc[3][2][4];
#pragma unroll
  for (int z = 0; z < 3; z++)
#pragma unroll
    for (int mi = 0; mi < 2; mi++)
#pragma unroll
      for (int ni = 0; ni < 4; ni++) acc[z][mi][ni] = (f32x4){0.f, 0.f, 0.f, 0.f};

  for (int ks = 0; ks < 8; ++ks) {
    const int k0 = ks * 32;
    __syncthreads();
#pragma unroll
    for (int i = 0; i < 4; ++i) {
      int f = tid + i * 256;
      int row = f >> 3, c4 = (f & 7) * 4;
      float4 v = *(const float4*)(x + (size_t)(mb + row) * DIM + k0 + c4);
      us4 bv = { f2bf(v.x), f2bf(v.y), f2bf(v.z), f2bf(v.w) };
      *(us4*)&A_lds[row][c4] = bv;
    }
#pragma unroll
    for (int z = 0; z < 3; z++)
#pragma unroll
      for (int i = 0; i < 2; ++i) {
        int f = tid + i * 256;
        int row = f >> 3, c4 = (f & 7) * 4;
        float4 v = *(const float4*)(Ws[z] + (size_t)(nb + row) * DIM + k0 + c4);
        us4 bv = { f2bf(v.x), f2bf(v.y), f2bf(v.z), f2bf(v.w) };
        *(us4*)&B_lds[z][row][c4] = bv;
      }
    __syncthreads();
    bf16x8 a[2];
#pragma unroll
    for (int mi = 0; mi < 2; mi++) a[mi] = *(const bf16x8*)&A_lds[w * 32 + mi * 16 + lo][hi * 8];
#pragma unroll
    for (int z = 0; z < 3; z++) {
      bf16x8 bfr[4];
#pragma unroll
      for (int ni = 0; ni < 4; ni++) bfr[ni] = *(const bf16x8*)&B_lds[z][ni * 16 + lo][hi * 8];
#pragma unroll
      for (int mi = 0; mi < 2; mi++)
#pragma unroll
        for (int ni = 0; ni < 4; ni++)
          acc[z][mi][ni] = __builtin_amdgcn_mfma_f32_16x16x32_bf16(a[mi], bfr[ni], acc[z][mi][ni], 0, 0, 0);
    }
  }

  // Q epilogue (fragment order, pre-scaled into log2 domain)
#pragma unroll
  for (int mi = 0; mi < 2; mi++) {
    int r0 = mb + w * 32 + mi * 16 + hi * 4;
#pragma unroll
    for (int ni = 0; ni < 4; ni++) {
      int d = nb + ni * 16 + lo;
      int kkq = d >> 5, hiq = (d >> 3) & 3, eq = d & 7;
#pragma unroll
      for (int j = 0; j < 4; j++) {
        int srow = r0 + j;
        int s16 = srow >> 4, loq = srow & 15;
        size_t byte = ((size_t)(s16 * 8 + kkq) << 10) + ((hiq * 16 + loq) << 4) + eq * 2;
        *(unsigned short*)(qbf + byte) = f2bf(acc[0][mi][ni][j] * QSCALE);
      }
    }
  }
  // K epilogue (fragment order)
#pragma unroll
  for (int mi = 0; mi < 2; mi++) {
    int r0 = mb + w * 32 + mi * 16 + hi * 4;
#pragma unroll
    for (int ni = 0; ni < 4; ni++) {
      int d = nb + ni * 16 + lo;
      int kkk = d >> 5, hik = (d >> 3) & 3, ek = d & 7;
#pragma unroll
      for (int j = 0; j < 4; j++) {
        int srow = r0 + j;
        int bb = srow >> 12, sl = srow & 4095;
        int t = sl >> 6, r = sl & 63;
        int nf = r >> 4, lok = r & 15;
        size_t byte = ((size_t)(bb * 64 + t)) * KVT_BYTES +
                      ((size_t)(nf * 8 + kkk) << 10) + ((hik * 16 + lok) << 4) + ek * 2;
        *(unsigned short*)(kv + byte) = f2bf(acc[1][mi][ni][j]);
      }
    }
  }
  // V epilogue (fragment order, 8B stores)
#pragma unroll
  for (int mi = 0; mi < 2; mi++) {
    int s0 = mb + w * 32 + mi * 16 + hi * 4;
    int bb = s0 >> 12;
    int t = (s0 >> 6) & 63;
    int s_t = s0 & 63;
    int ksI = s_t >> 5;
    int hf = (s_t >> 3) & 3;
    int e0 = s_t & 7;
#pragma unroll
    for (int ni = 0; ni < 4; ni++) {
      int d = nb + ni * 16 + lo;
      int n = d >> 4;
      us4 pv = { f2bf(acc[2][mi][ni][0]), f2bf(acc[2][mi][ni][1]),
                 f2bf(acc[2][mi][ni][2]), f2bf(acc[2][mi][ni][3]) };
      size_t byte = ((size_t)(bb * 64 + t)) * KVT_BYTES + 32768 +
                    ((size_t)(ksI * 16 + n) << 10) + ((hf * 16 + lo) << 4) + e0 * 2;
      *(us4*)(kv + byte) = pv;
    }
  }
}

// ---------------- Kernel 2a: attn_fa (8 waves x 16 rows, swapped QK^T, half-split) ----------------
__global__ __launch_bounds__(512, 1) void attn_fa(
    const char* __restrict__ qbf, const char* __restrict__ kv,
    float* __restrict__ out, unsigned short* __restrict__ o1,
    unsigned short* __restrict__ o2, unsigned short* __restrict__ o3,
    float* __restrict__ ml)
{
  __shared__ char KV_lds[2][KVT_BYTES];        // 128KB double buffer (linear frags)
  __shared__ unsigned short P_lds[8][16][72];

  const int tid = threadIdx.x;
  const int lane = tid & 63;
  const int w = tid >> 6;
  const int lo = lane & 15, hi = lane >> 4;
  const int id = blockIdx.x;
  const int x = id & 7;
  const int b = x >> 1;
  const int v = id >> 3;
  const int p = v & 15;
  const int cbase = ((v >> 4) << 1) | (x & 1);   // 0..3

  const char* kv_base = kv + (size_t)b * 64 * KVT_BYTES;

  auto stageKV = [&](int t, int buf) {
    const char* src = kv_base + (size_t)t * KVT_BYTES + tid * 16;
    char* dst = &KV_lds[buf][0] + tid * 16;
#pragma unroll
    for (int i = 0; i < 8; ++i) {
      __builtin_amdgcn_global_load_lds(
          (const __attribute__((address_space(1))) void*)(src + i * 8192),
          (__attribute__((address_space(3))) void*)(dst + i * 8192),
          16, 0, 0);
    }
  };

  for (int task = 0; task < 2; ++task) {
    const int u = task ? (15 - p) + 16 : p;      // run: p then 31-p
    const int cc = task ? (3 - cbase) : cbase;
    const int nt = 2 * u + 2;
    const int t0 = (nt * cc) >> 2;
    const int t1 = (nt * (cc + 1)) >> 2;
    const int qrow0 = u * 128 + w * 16;          // wave's first q row (in batch)
    const int rbase = b * SEQ + qrow0;
    float* mlc = ml + (size_t)cc * 16384 * 2;

    if (t0 >= t1) {   // empty chunk (u=0: cc 0 and 2)
      if (lane < 16) {
        mlc[(size_t)(rbase + lane) * 2 + 0] = -3e38f;
        mlc[(size_t)(rbase + lane) * 2 + 1] = 0.f;
      }
      if (cc == 0) {
#pragma unroll
        for (int j = 0; j < 16; j++)
#pragma unroll
          for (int n = 0; n < 4; n++)
            out[(size_t)(rbase + j) * DIM + n * 64 + lane] = 0.f;
      }
      continue;
    }

    // Q fragments pinned (issued BEFORE stages; vmcnt-counted together)
    bf16x8 qf[8];
    {
      const char* qp = qbf + ((size_t)(b * 256 + u * 8 + w) << 13) + lane * 16;
#pragma unroll
      for (int kk = 0; kk < 8; kk++)
        qf[kk] = *(const bf16x8*)(qp + kk * 1024);
    }

    stageKV(t0, 0);
    if (t0 + 1 < t1) stageKV(t0 + 1, 1);

    float m_run = -3e38f, l_run = 0.f;   // per-lane: q-row = lo
    f32x4 o_acc[16];
#pragma unroll
    for (int n = 0; n < 16; n++) o_acc[n] = (f32x4){0.f, 0.f, 0.f, 0.f};

    for (int t = t0; t < t1; ++t) {
      const int cur = (t - t0) & 1;

      if (t + 1 < t1) {
        asm volatile("s_waitcnt vmcnt(8)" ::: "memory");
      } else {
        asm volatile("s_waitcnt vmcnt(0)" ::: "memory");
      }
      __builtin_amdgcn_sched_barrier(0);
      __builtin_amdgcn_s_barrier();   // buffer cur fully staged for all waves

      const char* kt = &KV_lds[cur][0] + lane * 16;
      const char* vt = &KV_lds[cur][32768] + lane * 16;
      const bool needmask = (t * KVBLK + KVBLK - 1) > qrow0;
      const int qg = qrow0 + lo;

      // ---- half 0: QK^T nf=0,1 (S^T, swapped; kv = nf*16+hi*4+j) ----
      f32x4 sfT0[2];
      __builtin_amdgcn_s_setprio(1);
#pragma unroll
      for (int nf = 0; nf < 2; nf++) {
        bf16x8 kf[8];
#pragma unroll
        for (int kk = 0; kk < 8; kk++)
          kf[kk] = *(const bf16x8*)(kt + ((nf * 8 + kk) << 10));
        f32x4 a = (f32x4){0.f, 0.f, 0.f, 0.f};
#pragma unroll
        for (int kk = 0; kk < 8; kk++)
          a = __builtin_amdgcn_mfma_f32_16x16x32_bf16(kf[kk], qf[kk], a, 0, 0, 0);
        sfT0[nf] = a;
      }
      // issue QK^T nf=2,3 immediately (independent of softmax01 below)
      f32x4 sfT1[2];
#pragma unroll
      for (int nf = 2; nf < 4; nf++) {
        bf16x8 kf[8];
#pragma unroll
        for (int kk = 0; kk < 8; kk++)
          kf[kk] = *(const bf16x8*)(kt + ((nf * 8 + kk) << 10));
        f32x4 a = (f32x4){0.f, 0.f, 0.f, 0.f};
#pragma unroll
        for (int kk = 0; kk < 8; kk++)
          a = __builtin_amdgcn_mfma_f32_16x16x32_bf16(kf[kk], qf[kk], a, 0, 0, 0);
        sfT1[nf - 2] = a;
      }
      __builtin_amdgcn_s_setprio(0);

      // va = V frags for kv 0..31 (half0); latency hides under softmax01
      bf16x8 va[16];
#pragma unroll
      for (int i = 0; i < 16; i++)
        va[i] = *(const bf16x8*)(vt + (i << 10));

      // ---- softmax update, half 0 (overlaps in-flight nf23 MFMAs) ----
      if (needmask) {
#pragma unroll
        for (int nf = 0; nf < 2; nf++)
#pragma unroll
          for (int j = 0; j < 4; j++) {
            int kg = t * KVBLK + nf * 16 + hi * 4 + j;
            if (kg > qg) sfT0[nf][j] = -__builtin_inff();
          }
      }
      {
        float vnew = sfT0[0][0];
#pragma unroll
        for (int nf = 0; nf < 2; nf++)
#pragma unroll
          for (int j = 0; j < 4; j++) vnew = fmaxf(vnew, sfT0[nf][j]);
        vnew = fmaxf(vnew, __shfl_xor(vnew, 16));
        vnew = fmaxf(vnew, __shfl_xor(vnew, 32));
        if (__any(vnew > m_run + DEFER_THR)) {
          float mn = fmaxf(m_run, vnew);
          float alpha = exp2f(m_run - mn);
          m_run = mn;
          l_run *= alpha;
#pragma unroll
          for (int j = 0; j < 4; j++) {
            float aj = __shfl(alpha, (lane & 48) + ((lane >> 4) & 3) * 4 + j);
#pragma unroll
            for (int n = 0; n < 16; n++) o_acc[n][j] *= aj;
          }
        }
        float sum = 0.f;
#pragma unroll
        for (int nf = 0; nf < 2; nf++)
#pragma unroll
          for (int j = 0; j < 4; j++) {
            sfT0[nf][j] = exp2f(sfT0[nf][j] - m_run);
            sum += sfT0[nf][j];
          }
        l_run += sum;
      }
      // P half0 -> LDS cols 0..31 (4 packed dwords), read pa0
#pragma unroll
      for (int nf = 0; nf < 2; nf++)
#pragma unroll
        for (int h2 = 0; h2 < 2; h2++) {
          unsigned int pk;
          asm("v_cvt_pk_bf16_f32 %0, %1, %2"
              : "=v"(pk) : "v"(sfT0[nf][h2 * 2]), "v"(sfT0[nf][h2 * 2 + 1]));
          *(unsigned int*)&P_lds[w][lo][nf * 16 + hi * 4 + h2 * 2] = pk;
        }
      bf16x8 pa0 = *(const bf16x8*)&P_lds[w][lo][hi * 8];

      // ---- PV half 0 (pa0 x va) ----
      __builtin_amdgcn_s_setprio(1);
#pragma unroll
      for (int n = 0; n < 16; n++)
        o_acc[n] = __builtin_amdgcn_mfma_f32_16x16x32_bf16(pa0, va[n], o_acc[n], 0, 0, 0);
      __builtin_amdgcn_s_setprio(0);

      // ---- softmax update, half 1 (overlaps PV0 MFMAs except rare rescale) ----
      if (needmask) {
#pragma unroll
        for (int nf = 0; nf < 2; nf++)
#pragma unroll
          for (int j = 0; j < 4; j++) {
            int kg = t * KVBLK + (nf + 2) * 16 + hi * 4 + j;
            if (kg > qg) sfT1[nf][j] = -__builtin_inff();
          }
      }
      {
        float vnew = sfT1[0][0];
#pragma unroll
        for (int nf = 0; nf < 2; nf++)
#pragma unroll
          for (int j = 0; j < 4; j++) vnew = fmaxf(vnew, sfT1[nf][j]);
        vnew = fmaxf(vnew, __shfl_xor(vnew, 16));
        vnew = fmaxf(vnew, __shfl_xor(vnew, 32));
        if (__any(vnew > m_run + DEFER_THR)) {
          float mn = fmaxf(m_run, vnew);
          float alpha = exp2f(m_run - mn);
          m_run = mn;
          l_run *= alpha;
#pragma unroll
          for (int j = 0; j < 4; j++) {
            float aj = __shfl(alpha, (lane & 48) + ((lane >> 4) & 3) * 4 + j);
#pragma unroll
            for (int n = 0; n < 16; n++) o_acc[n][j] *= aj;
          }
        }
        float sum = 0.f;
#pragma unroll
        for (int nf = 0; nf < 2; nf++)
#pragma unroll
          for (int j = 0; j < 4; j++) {
            sfT1[nf][j] = exp2f(sfT1[nf][j] - m_run);
            sum += sfT1[nf][j];
          }
        l_run += sum;
      }
      // P half1 -> LDS cols 32..63, read pa1
#pragma unroll
      for (int nf = 0; nf < 2; nf++)
#pragma unroll
        for (int h2 = 0; h2 < 2; h2++) {
          unsigned int pk;
          asm("v_cvt_pk_bf16_f32 %0, %1, %2"
              : "=v"(pk) : "v"(sfT1[nf][h2 * 2]), "v"(sfT1[nf][h2 * 2 + 1]));
          *(unsigned int*)&P_lds[w][lo][32 + nf * 16 + hi * 4 + h2 * 2] = pk;
        }
      bf16x8 pa1 = *(const bf16x8*)&P_lds[w][lo][32 + hi * 8];

      // ---- PV half 1 (pa1 x vb, loaded inline) ----
      __builtin_amdgcn_s_setprio(1);
#pragma unroll
      for (int g = 0; g < 4; g++) {
        bf16x8 vb[4];
#pragma unroll
        for (int k = 0; k < 4; k++)
          vb[k] = *(const bf16x8*)(vt + ((16 + g * 4 + k) << 10));
#pragma unroll
        for (int k = 0; k < 4; k++) {
          int n = g * 4 + k;
          o_acc[n] = __builtin_amdgcn_mfma_f32_16x16x32_bf16(pa1, vb[k], o_acc[n], 0, 0, 0);
        }
      }
      __builtin_amdgcn_s_setprio(0);

      __builtin_amdgcn_sched_barrier(0);
      __builtin_amdgcn_s_barrier();   // all waves done reading buffer cur
      if (t + 2 < t1) stageKV(t + 2, cur);
    }

    // epilogue: reduce lazy-l across hi groups; broadcast inv to q-rows
    l_run += __shfl_xor(l_run, 16);
    l_run += __shfl_xor(l_run, 32);
    float inv = (l_run > 0.f) ? 1.f / l_run : 0.f;

    unsigned short* opc = (cc == 1) ? o1 : (cc == 2) ? o2 : o3;
#pragma unroll
    for (int j = 0; j < 4; j++) {
      float invj = __shfl(inv, (lane & 48) + ((lane >> 4) & 3) * 4 + j);
      int r = rbase + hi * 4 + j;
      if (cc == 0) {
        float* orow = out + (size_t)r * DIM;
#pragma unroll
        for (int n = 0; n < 16; n++)
          orow[n * 16 + lo] = o_acc[n][j] * invj;
      } else {
        unsigned short* orow = opc + (size_t)r * DIM;
#pragma unroll
        for (int n = 0; n < 16; n++)
          orow[n * 16 + lo] = f2bf(o_acc[n][j] * invj);
      }
    }
    if (hi == 0) {   // lane lo holds (m,l) for q-row lo
      mlc[(size_t)(rbase + lo) * 2 + 0] = m_run;
      mlc[(size_t)(rbase + lo) * 2 + 1] = l_run;
    }
  }
}

// ---------------- Kernel 2b: 4-way merge (m in log2 domain -> exp2) ----------------
__global__ __launch_bounds__(256) void merge4(
    const float* __restrict__ ml,
    const unsigned short* __restrict__ o1, const unsigned short* __restrict__ o2,
    const unsigned short* __restrict__ o3, float* __restrict__ out)
{
  int r = blockIdx.x * 4 + (threadIdx.x >> 6);
  int c4 = (threadIdx.x & 63) * 4;
  float m0 = ml[(size_t)r*2],           l0 = ml[(size_t)r*2+1];
  float m1 = ml[(size_t)(16384+r)*2],   l1 = ml[(size_t)(16384+r)*2+1];
  float m2 = ml[(size_t)(32768+r)*2],   l2 = ml[(size_t)(32768+r)*2+1];
  float m3 = ml[(size_t)(49152+r)*2],   l3 = ml[(size_t)(49152+r)*2+1];
  float M = fmaxf(fmaxf(m0, m1), fmaxf(m2, m3));
  float w0 = l0 * exp2f(m0 - M);
  float w1 = l1 * exp2f(m1 - M);
  float w2 = l2 * exp2f(m2 - M);
  float w3 = l3 * exp2f(m3 - M);
  float inv = 1.f / (w0 + w1 + w2 + w3);
  float4 o0 = *(const float4*)(out + (size_t)r * DIM + c4);
  us4 a  = *(const us4*)(o1 + (size_t)r * DIM + c4);
  us4 bq = *(const us4*)(o2 + (size_t)r * DIM + c4);
  us4 cq = *(const us4*)(o3 + (size_t)r * DIM + c4);
  float4 res;
  res.x = (w0*o0.x + w1*bf2f(a.x) + w2*bf2f(bq.x) + w3*bf2f(cq.x)) * inv;
  res.y = (w0*o0.y + w1*bf2f(a.y) + w2*bf2f(bq.y) + w3*bf2f(cq.y)) * inv;
  res.z = (w0*o0.z + w1*bf2f(a.z) + w2*bf2f(bq.z) + w3*bf2f(cq.z)) * inv;
  res.w = (w0*o0.w + w1*bf2f(a.w) + w2*bf2f(bq.w) + w3*bf2f(cq.w)) * inv;
  *(float4*)(out + (size_t)r * DIM + c4) = res;
}

extern "C" void kernel_launch(void* const* d_in, const int* in_sizes, int n_in,
                              void* d_out, int out_size, void* d_ws, size_t ws_size,
                              hipStream_t stream) {
  const float* x  = (const float*)d_in[0];
  const float* Wq = (const float*)d_in[1];
  const float* Wk = (const float*)d_in[2];
  const float* Wv = (const float*)d_in[3];
  char* ws = (char*)d_ws;
  char* qbf = ws + QB_OFF;
  char* kv  = ws + KV_OFF;
  unsigned short* o1 = (unsigned short*)(ws + O1_OFF);
  unsigned short* o2 = (unsigned short*)(ws + O2_OFF);
  unsigned short* o3 = (unsigned short*)(ws + O3_OFF);
  float* ml = (float*)(ws + ML_OFF);
  float* out = (float*)d_out;

  qkv_gemm<<<dim3(128, 4), 256, 0, stream>>>(x, Wq, Wk, Wv, qbf, kv);
  attn_fa<<<dim3(256), 512, 0, stream>>>(qbf, kv, out, o1, o2, o3, ml);
  merge4<<<dim3(4096), 256, 0, stream>>>(ml, o1, o2, o3, out);
}

// Round 22
// 86.335 us; speedup vs baseline: 1.0589x; 1.0589x over previous
//
#include <hip/hip_runtime.h>
#include <hip/hip_bf16.h>

// Problem: B=4, S=4096, D=256 single-head causal attention, fp32 in/out.
// ALL tensors in MFMA-fragment order (fragment = contiguous 1KB, lane*16):
//  Qf @0:  strip s16=row>>4: 8KB; frag kk at (s16*8+kk)*1024.
//          Q PRE-SCALED by 0.0625*log2(e) -> scores in LOG2 domain (bare exp2).
//  KV @8MB: per (batch, kv-tile t<64) 64KB: K frags [0..32K) (nf*8+kk)*1024;
//           V frags [32K..64K) (ks*16+n)*1024
//  O1/O2/O3 bf16 partials @24/32/40MB; ML fp32 [4][16384][2] @48MB (m in log2).
// attn_fa: 256 blocks x 512 thr (8 waves x 16 rows, 1 block/CU, 2 waves/SIMD).
// Swapped QK^T (S^T = mfma(K,Q), q lane-local), log2 softmax, defer-max,
// lazy-l, va-hoist, counted-vmcnt KV dbuf. (R20 configuration — measured best;
// R21's intra-tile half-split regressed and is reverted.)

#define SEQ 4096
#define DIM 256
#define NBATCH 4
#define KVBLK 64
#define KVT_BYTES 65536

#define QB_OFF   0
#define KV_OFF   (8u*1024*1024)
#define O1_OFF   (24u*1024*1024)
#define O2_OFF   (32u*1024*1024)
#define O3_OFF   (40u*1024*1024)
#define ML_OFF   (48u*1024*1024)

// 0.0625 * log2(e)
#define QSCALE 0.09016844f
// 8 nats in bits
#define DEFER_THR 11.5415603f

typedef __attribute__((ext_vector_type(8))) short bf16x8;
typedef __attribute__((ext_vector_type(4))) float f32x4;
typedef __attribute__((ext_vector_type(4))) unsigned short us4;

static __device__ inline unsigned short f2bf(float f) {
  unsigned int u = __float_as_uint(f);
  u += 0x7FFFu + ((u >> 16) & 1u);
  return (unsigned short)(u >> 16);
}
static __device__ inline float bf2f(unsigned short u) {
  return __uint_as_float(((unsigned int)u) << 16);
}

// ---------------- Kernel 1: fused QKV projection (z fused; x read once) ----------------
// grid (128, 4), block 256 (4 waves, 2 blocks/CU).
__global__ __launch_bounds__(256) void qkv_gemm(
    const float* __restrict__ x, const float* __restrict__ Wq,
    const float* __restrict__ Wk, const float* __restrict__ Wv,
    char* __restrict__ qbf, char* __restrict__ kv)
{
  __shared__ unsigned short A_lds[128][40];
  __shared__ unsigned short B_lds[3][64][40];

  const int tid = threadIdx.x;
  const int lane = tid & 63;
  const int w = tid >> 6;
  const int lo = lane & 15, hi = lane >> 4;
  const int mb = blockIdx.x * 128;
  const int nb = blockIdx.y * 64;
  const float* Ws[3] = { Wq, Wk, Wv };

  f32x4 acc[3][2][4];
#pragma unroll
  for (int z = 0; z < 3; z++)
#pragma unroll
    for (int mi = 0; mi < 2; mi++)
#pragma unroll
      for (int ni = 0; ni < 4; ni++) acc[z][mi][ni] = (f32x4){0.f, 0.f, 0.f, 0.f};

  for (int ks = 0; ks < 8; ++ks) {
    const int k0 = ks * 32;
    __syncthreads();
#pragma unroll
    for (int i = 0; i < 4; ++i) {
      int f = tid + i * 256;
      int row = f >> 3, c4 = (f & 7) * 4;
      float4 v = *(const float4*)(x + (size_t)(mb + row) * DIM + k0 + c4);
      us4 bv = { f2bf(v.x), f2bf(v.y), f2bf(v.z), f2bf(v.w) };
      *(us4*)&A_lds[row][c4] = bv;
    }
#pragma unroll
    for (int z = 0; z < 3; z++)
#pragma unroll
      for (int i = 0; i < 2; ++i) {
        int f = tid + i * 256;
        int row = f >> 3, c4 = (f & 7) * 4;
        float4 v = *(const float4*)(Ws[z] + (size_t)(nb + row) * DIM + k0 + c4);
        us4 bv = { f2bf(v.x), f2bf(v.y), f2bf(v.z), f2bf(v.w) };
        *(us4*)&B_lds[z][row][c4] = bv;
      }
    __syncthreads();
    bf16x8 a[2];
#pragma unroll
    for (int mi = 0; mi < 2; mi++) a[mi] = *(const bf16x8*)&A_lds[w * 32 + mi * 16 + lo][hi * 8];
#pragma unroll
    for (int z = 0; z < 3; z++) {
      bf16x8 bfr[4];
#pragma unroll
      for (int ni = 0; ni < 4; ni++) bfr[ni] = *(const bf16x8*)&B_lds[z][ni * 16 + lo][hi * 8];
#pragma unroll
      for (int mi = 0; mi < 2; mi++)
#pragma unroll
        for (int ni = 0; ni < 4; ni++)
          acc[z][mi][ni] = __builtin_amdgcn_mfma_f32_16x16x32_bf16(a[mi], bfr[ni], acc[z][mi][ni], 0, 0, 0);
    }
  }

  // Q epilogue (fragment order, pre-scaled into log2 domain)
#pragma unroll
  for (int mi = 0; mi < 2; mi++) {
    int r0 = mb + w * 32 + mi * 16 + hi * 4;
#pragma unroll
    for (int ni = 0; ni < 4; ni++) {
      int d = nb + ni * 16 + lo;
      int kkq = d >> 5, hiq = (d >> 3) & 3, eq = d & 7;
#pragma unroll
      for (int j = 0; j < 4; j++) {
        int srow = r0 + j;
        int s16 = srow >> 4, loq = srow & 15;
        size_t byte = ((size_t)(s16 * 8 + kkq) << 10) + ((hiq * 16 + loq) << 4) + eq * 2;
        *(unsigned short*)(qbf + byte) = f2bf(acc[0][mi][ni][j] * QSCALE);
      }
    }
  }
  // K epilogue (fragment order)
#pragma unroll
  for (int mi = 0; mi < 2; mi++) {
    int r0 = mb + w * 32 + mi * 16 + hi * 4;
#pragma unroll
    for (int ni = 0; ni < 4; ni++) {
      int d = nb + ni * 16 + lo;
      int kkk = d >> 5, hik = (d >> 3) & 3, ek = d & 7;
#pragma unroll
      for (int j = 0; j < 4; j++) {
        int srow = r0 + j;
        int bb = srow >> 12, sl = srow & 4095;
        int t = sl >> 6, r = sl & 63;
        int nf = r >> 4, lok = r & 15;
        size_t byte = ((size_t)(bb * 64 + t)) * KVT_BYTES +
                      ((size_t)(nf * 8 + kkk) << 10) + ((hik * 16 + lok) << 4) + ek * 2;
        *(unsigned short*)(kv + byte) = f2bf(acc[1][mi][ni][j]);
      }
    }
  }
  // V epilogue (fragment order, 8B stores)
#pragma unroll
  for (int mi = 0; mi < 2; mi++) {
    int s0 = mb + w * 32 + mi * 16 + hi * 4;
    int bb = s0 >> 12;
    int t = (s0 >> 6) & 63;
    int s_t = s0 & 63;
    int ksI = s_t >> 5;
    int hf = (s_t >> 3) & 3;
    int e0 = s_t & 7;
#pragma unroll
    for (int ni = 0; ni < 4; ni++) {
      int d = nb + ni * 16 + lo;
      int n = d >> 4;
      us4 pv = { f2bf(acc[2][mi][ni][0]), f2bf(acc[2][mi][ni][1]),
                 f2bf(acc[2][mi][ni][2]), f2bf(acc[2][mi][ni][3]) };
      size_t byte = ((size_t)(bb * 64 + t)) * KVT_BYTES + 32768 +
                    ((size_t)(ksI * 16 + n) << 10) + ((hf * 16 + lo) << 4) + e0 * 2;
      *(us4*)(kv + byte) = pv;
    }
  }
}

// ---------------- Kernel 2a: attn_fa (8 waves x 16 rows, swapped QK^T) ----------------
__global__ __launch_bounds__(512, 1) void attn_fa(
    const char* __restrict__ qbf, const char* __restrict__ kv,
    float* __restrict__ out, unsigned short* __restrict__ o1,
    unsigned short* __restrict__ o2, unsigned short* __restrict__ o3,
    float* __restrict__ ml)
{
  __shared__ char KV_lds[2][KVT_BYTES];        // 128KB double buffer (linear frags)
  __shared__ unsigned short P_lds[8][16][88];  // 176B rows

  const int tid = threadIdx.x;
  const int lane = tid & 63;
  const int w = tid >> 6;
  const int lo = lane & 15, hi = lane >> 4;
  const int id = blockIdx.x;
  const int x = id & 7;
  const int b = x >> 1;
  const int v = id >> 3;
  const int p = v & 15;
  const int cbase = ((v >> 4) << 1) | (x & 1);   // 0..3

  const char* kv_base = kv + (size_t)b * 64 * KVT_BYTES;

  auto stageKV = [&](int t, int buf) {
    const char* src = kv_base + (size_t)t * KVT_BYTES + tid * 16;
    char* dst = &KV_lds[buf][0] + tid * 16;
#pragma unroll
    for (int i = 0; i < 8; ++i) {
      __builtin_amdgcn_global_load_lds(
          (const __attribute__((address_space(1))) void*)(src + i * 8192),
          (__attribute__((address_space(3))) void*)(dst + i * 8192),
          16, 0, 0);
    }
  };

  for (int task = 0; task < 2; ++task) {
    const int u = task ? (15 - p) + 16 : p;      // run: p then 31-p
    const int cc = task ? (3 - cbase) : cbase;
    const int nt = 2 * u + 2;
    const int t0 = (nt * cc) >> 2;
    const int t1 = (nt * (cc + 1)) >> 2;
    const int qrow0 = u * 128 + w * 16;          // wave's first q row (in batch)
    const int rbase = b * SEQ + qrow0;
    float* mlc = ml + (size_t)cc * 16384 * 2;

    if (t0 >= t1) {   // empty chunk (u=0: cc 0 and 2)
      if (lane < 16) {
        mlc[(size_t)(rbase + lane) * 2 + 0] = -3e38f;
        mlc[(size_t)(rbase + lane) * 2 + 1] = 0.f;
      }
      if (cc == 0) {
#pragma unroll
        for (int j = 0; j < 16; j++)
#pragma unroll
          for (int n = 0; n < 4; n++)
            out[(size_t)(rbase + j) * DIM + n * 64 + lane] = 0.f;
      }
      continue;
    }

    // Q fragments pinned (issued BEFORE stages; vmcnt-counted together)
    bf16x8 qf[8];
    {
      const char* qp = qbf + ((size_t)(b * 256 + u * 8 + w) << 13) + lane * 16;
#pragma unroll
      for (int kk = 0; kk < 8; kk++)
        qf[kk] = *(const bf16x8*)(qp + kk * 1024);
    }

    stageKV(t0, 0);
    if (t0 + 1 < t1) stageKV(t0 + 1, 1);

    float m_run = -3e38f, l_run = 0.f;   // per-lane: q-row = lo
    f32x4 o_acc[16];
#pragma unroll
    for (int n = 0; n < 16; n++) o_acc[n] = (f32x4){0.f, 0.f, 0.f, 0.f};

    for (int t = t0; t < t1; ++t) {
      const int cur = (t - t0) & 1;

      if (t + 1 < t1) {
        asm volatile("s_waitcnt vmcnt(8)" ::: "memory");
      } else {
        asm volatile("s_waitcnt vmcnt(0)" ::: "memory");
      }
      __builtin_amdgcn_sched_barrier(0);
      __builtin_amdgcn_s_barrier();   // buffer cur fully staged for all waves

      const char* kt = &KV_lds[cur][0] + lane * 16;

      // S^T = K Q^T (swapped operands; log2 domain). Lane holds
      // S[kv=nf*16+hi*4+j][q=lo] in sfT[nf][j].
      f32x4 sfT[4];
      __builtin_amdgcn_s_setprio(1);
#pragma unroll
      for (int nf = 0; nf < 4; nf++) {
        bf16x8 kf[8];
#pragma unroll
        for (int kk = 0; kk < 8; kk++)
          kf[kk] = *(const bf16x8*)(kt + ((nf * 8 + kk) << 10));
        f32x4 a = (f32x4){0.f, 0.f, 0.f, 0.f};
#pragma unroll
        for (int kk = 0; kk < 8; kk++)
          a = __builtin_amdgcn_mfma_f32_16x16x32_bf16(kf[kk], qf[kk], a, 0, 0, 0);
        sfT[nf] = a;
      }
      __builtin_amdgcn_s_setprio(0);

      // hoist the 16 'va' V-fragments (R18-proven)
      const char* vt = &KV_lds[cur][32768] + lane * 16;
      bf16x8 va[16];
#pragma unroll
      for (int i = 0; i < 16; i++)
        va[i] = *(const bf16x8*)(vt + (i << 10));

      // causal mask: kg = t*64+nf*16+hi*4+j, qg = qrow0+lo
      if ((t * KVBLK + KVBLK - 1) > qrow0) {
        int qg = qrow0 + lo;
#pragma unroll
        for (int nf = 0; nf < 4; nf++) {
#pragma unroll
          for (int j = 0; j < 4; j++) {
            int kg = t * KVBLK + nf * 16 + hi * 4 + j;
            if (kg > qg) sfT[nf][j] = -__builtin_inff();
          }
        }
      }

      // online softmax (log2): in-lane max over 16, then 2 shfl across hi
      float vnew = sfT[0][0];
#pragma unroll
      for (int nf = 0; nf < 4; nf++)
#pragma unroll
        for (int j = 0; j < 4; j++) vnew = fmaxf(vnew, sfT[nf][j]);
      vnew = fmaxf(vnew, __shfl_xor(vnew, 16));
      vnew = fmaxf(vnew, __shfl_xor(vnew, 32));

      if (__any(vnew > m_run + DEFER_THR)) {
        float mn = fmaxf(m_run, vnew);
        float alpha = exp2f(m_run - mn);
        m_run = mn;
        l_run *= alpha;
        // broadcast alpha from q=lo lanes to this lane's q-rows hi*4+j
#pragma unroll
        for (int j = 0; j < 4; j++) {
          float aj = __shfl(alpha, (lane & 48) + ((lane >> 4) & 3) * 4 + j);
#pragma unroll
          for (int n = 0; n < 16; n++) o_acc[n][j] *= aj;
        }
      }
      // P^T = exp2(S^T - m); lazy per-lane l partial
      {
        float sum = 0.f;
#pragma unroll
        for (int nf = 0; nf < 4; nf++)
#pragma unroll
          for (int j = 0; j < 4; j++) {
            sfT[nf][j] = exp2f(sfT[nf][j] - m_run);
            sum += sfT[nf][j];
          }
        l_run += sum;
      }

      // P -> LDS: 8 packed bf16 dwords, row = q = lo, cols nf*16+hi*4+{j,j+1}
      // (compiler inserts counted lgkm waits for the read-back)
#pragma unroll
      for (int nf = 0; nf < 4; nf++) {
#pragma unroll
        for (int h2 = 0; h2 < 2; h2++) {
          unsigned int pk;
          asm("v_cvt_pk_bf16_f32 %0, %1, %2"
              : "=v"(pk) : "v"(sfT[nf][h2 * 2]), "v"(sfT[nf][h2 * 2 + 1]));
          *(unsigned int*)&P_lds[w][lo][nf * 16 + hi * 4 + h2 * 2] = pk;
        }
      }
      bf16x8 pa0 = *(const bf16x8*)&P_lds[w][lo][hi * 8];
      bf16x8 pa1 = *(const bf16x8*)&P_lds[w][lo][32 + hi * 8];

      // O += P V (va in registers; vb loaded inline per group)
      __builtin_amdgcn_s_setprio(1);
#pragma unroll
      for (int g = 0; g < 4; g++) {
        bf16x8 vb[4];
#pragma unroll
        for (int k = 0; k < 4; k++)
          vb[k] = *(const bf16x8*)(vt + ((16 + g * 4 + k) << 10));
#pragma unroll
        for (int k = 0; k < 4; k++) {
          int n = g * 4 + k;
          o_acc[n] = __builtin_amdgcn_mfma_f32_16x16x32_bf16(pa0, va[n], o_acc[n], 0, 0, 0);
          o_acc[n] = __builtin_amdgcn_mfma_f32_16x16x32_bf16(pa1, vb[k], o_acc[n], 0, 0, 0);
        }
      }
      __builtin_amdgcn_s_setprio(0);

      __builtin_amdgcn_sched_barrier(0);
      __builtin_amdgcn_s_barrier();   // all waves done reading buffer cur
      if (t + 2 < t1) stageKV(t + 2, cur);
    }

    // epilogue: reduce lazy-l across hi groups; broadcast inv to q-rows
    l_run += __shfl_xor(l_run, 16);
    l_run += __shfl_xor(l_run, 32);
    float inv = (l_run > 0.f) ? 1.f / l_run : 0.f;

    unsigned short* opc = (cc == 1) ? o1 : (cc == 2) ? o2 : o3;
#pragma unroll
    for (int j = 0; j < 4; j++) {
      float invj = __shfl(inv, (lane & 48) + ((lane >> 4) & 3) * 4 + j);
      int r = rbase + hi * 4 + j;
      if (cc == 0) {
        float* orow = out + (size_t)r * DIM;
#pragma unroll
        for (int n = 0; n < 16; n++)
          orow[n * 16 + lo] = o_acc[n][j] * invj;
      } else {
        unsigned short* orow = opc + (size_t)r * DIM;
#pragma unroll
        for (int n = 0; n < 16; n++)
          orow[n * 16 + lo] = f2bf(o_acc[n][j] * invj);
      }
    }
    if (hi == 0) {   // lane lo holds (m,l) for q-row lo
      mlc[(size_t)(rbase + lo) * 2 + 0] = m_run;
      mlc[(size_t)(rbase + lo) * 2 + 1] = l_run;
    }
  }
}

// ---------------- Kernel 2b: 4-way merge (m in log2 domain -> exp2) ----------------
__global__ __launch_bounds__(256) void merge4(
    const float* __restrict__ ml,
    const unsigned short* __restrict__ o1, const unsigned short* __restrict__ o2,
    const unsigned short* __restrict__ o3, float* __restrict__ out)
{
  int r = blockIdx.x * 4 + (threadIdx.x >> 6);
  int c4 = (threadIdx.x & 63) * 4;
  float m0 = ml[(size_t)r*2],           l0 = ml[(size_t)r*2+1];
  float m1 = ml[(size_t)(16384+r)*2],   l1 = ml[(size_t)(16384+r)*2+1];
  float m2 = ml[(size_t)(32768+r)*2],   l2 = ml[(size_t)(32768+r)*2+1];
  float m3 = ml[(size_t)(49152+r)*2],   l3 = ml[(size_t)(49152+r)*2+1];
  float M = fmaxf(fmaxf(m0, m1), fmaxf(m2, m3));
  float w0 = l0 * exp2f(m0 - M);
  float w1 = l1 * exp2f(m1 - M);
  float w2 = l2 * exp2f(m2 - M);
  float w3 = l3 * exp2f(m3 - M);
  float inv = 1.f / (w0 + w1 + w2 + w3);
  float4 o0 = *(const float4*)(out + (size_t)r * DIM + c4);
  us4 a  = *(const us4*)(o1 + (size_t)r * DIM + c4);
  us4 bq = *(const us4*)(o2 + (size_t)r * DIM + c4);
  us4 cq = *(const us4*)(o3 + (size_t)r * DIM + c4);
  float4 res;
  res.x = (w0*o0.x + w1*bf2f(a.x) + w2*bf2f(bq.x) + w3*bf2f(cq.x)) * inv;
  res.y = (w0*o0.y + w1*bf2f(a.y) + w2*bf2f(bq.y) + w3*bf2f(cq.y)) * inv;
  res.z = (w0*o0.z + w1*bf2f(a.z) + w2*bf2f(bq.z) + w3*bf2f(cq.z)) * inv;
  res.w = (w0*o0.w + w1*bf2f(a.w) + w2*bf2f(bq.w) + w3*bf2f(cq.w)) * inv;
  *(float4*)(out + (size_t)r * DIM + c4) = res;
}

extern "C" void kernel_launch(void* const* d_in, const int* in_sizes, int n_in,
                              void* d_out, int out_size, void* d_ws, size_t ws_size,
                              hipStream_t stream) {
  const float* x  = (const float*)d_in[0];
  const float* Wq = (const float*)d_in[1];
  const float* Wk = (const float*)d_in[2];
  const float* Wv = (const float*)d_in[3];
  char* ws = (char*)d_ws;
  char* qbf = ws + QB_OFF;
  char* kv  = ws + KV_OFF;
  unsigned short* o1 = (unsigned short*)(ws + O1_OFF);
  unsigned short* o2 = (unsigned short*)(ws + O2_OFF);
  unsigned short* o3 = (unsigned short*)(ws + O3_OFF);
  float* ml = (float*)(ws + ML_OFF);
  float* out = (float*)d_out;

  qkv_gemm<<<dim3(128, 4), 256, 0, stream>>>(x, Wq, Wk, Wv, qbf, kv);
  attn_fa<<<dim3(256), 512, 0, stream>>>(qbf, kv, out, o1, o2, o3, ml);
  merge4<<<dim3(4096), 256, 0, stream>>>(ml, o1, o2, o3, out);
}